// Round 1
// 955.381 us; speedup vs baseline: 1.1013x; 1.1013x over previous
//
#include <hip/hip_runtime.h>
#include <math.h>

#define B_ 128
#define T_ 512
#define H_ 512
#define E_ 512
#define VOUT 30000
#define M_ (T_*B_)

typedef __attribute__((ext_vector_type(8))) short short8;
typedef __attribute__((ext_vector_type(4))) float f32x4;

__device__ __forceinline__ ushort f2b(float f) {
    union { float f; unsigned int i; } c; c.f = f;
    unsigned int x = c.i;
    unsigned int r = (x + 0x7FFFu + ((x >> 16) & 1u)) >> 16;
    return (ushort)r;
}
// load 8 consecutive f32, convert to bf16x8 via HW packed converts (RNE)
__device__ __forceinline__ short8 cvt8(const float* p) {
    float4 a = *(const float4*)p;
    float4 b = *(const float4*)(p + 4);
    unsigned int r0, r1, r2, r3;
    asm("v_cvt_pk_bf16_f32 %0, %1, %2" : "=v"(r0) : "v"(a.x), "v"(a.y));
    asm("v_cvt_pk_bf16_f32 %0, %1, %2" : "=v"(r1) : "v"(a.z), "v"(a.w));
    asm("v_cvt_pk_bf16_f32 %0, %1, %2" : "=v"(r2) : "v"(b.x), "v"(b.y));
    asm("v_cvt_pk_bf16_f32 %0, %1, %2" : "=v"(r3) : "v"(b.z), "v"(b.w));
    union { unsigned int u[4]; short8 s; } u;
    u.u[0] = r0; u.u[1] = r1; u.u[2] = r2; u.u[3] = r3;
    return u.s;
}

// ---------------- small prep kernels ----------------

__global__ void emb_gather(const int* idx, const float* emb, float* x) {
    int b = blockIdx.x; int t = threadIdx.x;
    int row = idx[b];
    x[b*1024 + t]       = emb[(size_t)row*E_ + t];
    x[b*1024 + t + 256] = emb[(size_t)row*E_ + t + 256];
}

// A1[which][b][h] = sum_k h0[b,k]*W[h,k] + b_attn[h]
__global__ void prep_a1(const float* h0, const float* Wc, const float* bc,
                        const float* Wa, const float* ba, float* A1) {
    int b = blockIdx.x; int which = blockIdx.y;
    const float* W    = which ? Wa : Wc;
    const float* bias = which ? ba : bc;
    __shared__ float hs[H_];
    for (int k = threadIdx.x; k < H_; k += 256) hs[k] = h0[b*H_ + k];
    __syncthreads();
    for (int h = threadIdx.x; h < H_; h += 256) {
        const float* Wr = W + (size_t)h * 1536;
        float s = 0.f;
        for (int k = 0; k < H_; k += 4) {
            float4 w = *(const float4*)(Wr + k);
            s += hs[k]*w.x + hs[k+1]*w.y + hs[k+2]*w.z + hs[k+3]*w.w;
        }
        A1[((size_t)which*B_ + b)*H_ + h] = s + bias[h];
    }
}

// u[which][h] = sum_k Wcov[k] * W[h, 1024+k]   (rank-1 collapse of coverage branch)
__global__ void prep_u(const float* wcov_c, const float* W_c,
                       const float* wcov_a, const float* W_a, float* u) {
    int which = blockIdx.x; int h = threadIdx.x;
    const float* W  = which ? W_a : W_c;
    const float* wc = which ? wcov_a : wcov_c;
    const float* Wr = W + (size_t)h*1536 + 1024;
    float s = 0.f;
    for (int k = 0; k < H_; ++k) s += wc[k] * Wr[k];
    u[which*H_ + h] = s;
}

// ---------------- attention GEMM (fused score epilogue) ----------------
// scores[which][m] = sum_h relu( enc@W2^T + A1[b,h] + cov[b,t]*u[h] ) * v[h]
// m = t*B + b.  128x128 tile, 4 waves, 16x16x32 bf16 MFMA (f32 inputs staged->bf16).

#define BK 64
#define LDSS 72   // padded LDS row stride (elements)

__global__ __launch_bounds__(256)
void attn_gemm(const float* code_enc, const float* ast_enc,
               const float* code_W, const float* ast_W,
               const float* code_v, const float* ast_v,
               const float* code_cov, const float* ast_cov,
               const float* A1, const float* u, float* scores) {
    int which = blockIdx.y;
    const float* enc = which ? ast_enc : code_enc;
    const float* W   = which ? ast_W   : code_W;
    const float* vv  = which ? ast_v   : code_v;
    const float* cov = which ? ast_cov : code_cov;
    const float* A1w = A1 + (size_t)which * B_ * H_;
    const float* uw  = u + which * H_;
    float* sc = scores + (size_t)which * M_;

    // XCD-chunked swizzle: 2048 blocks, 8 XCDs. All 4 nt-mates (and 64
    // consecutive mt) land on one XCD -> enc tile fetched into one L2, not 4.
    int bid = blockIdx.x;
    int tile = ((bid & 7) << 8) + (bid >> 3);
    int mt = tile >> 2, nt = tile & 3;
    int m0 = mt * 128, n0 = nt * 128;

    __shared__ __align__(16) ushort As[128 * LDSS];
    __shared__ __align__(16) ushort Bs[128 * LDSS];

    int tid = threadIdx.x;
    int lane = tid & 63, wave = tid >> 6;
    int wm = wave >> 1, wn = wave & 1;
    int col = lane & 15, quad = lane >> 4;

    f32x4 acc[4][4];
    #pragma unroll
    for (int i = 0; i < 4; ++i)
        #pragma unroll
        for (int j = 0; j < 4; ++j) acc[i][j] = (f32x4)(0.f);

    for (int k0 = 0; k0 < H_; k0 += BK) {
        __syncthreads();
        #pragma unroll
        for (int it = 0; it < 4; ++it) {
            int c = it * 256 + tid;
            int row = c >> 3, c8 = (c & 7) * 8;
            *(short8*)(&As[row * LDSS + c8]) =
                cvt8(enc + (size_t)(m0 + row) * H_ + k0 + c8);
            *(short8*)(&Bs[row * LDSS + c8]) =
                cvt8(W + (size_t)(n0 + row) * 1536 + 512 + k0 + c8);
        }
        __syncthreads();
        #pragma unroll
        for (int kk = 0; kk < BK; kk += 32) {
            short8 af[4], bfr[4];
            #pragma unroll
            for (int i = 0; i < 4; ++i)
                af[i] = *(const short8*)(&As[(wm*64 + i*16 + col) * LDSS + kk + quad*8]);
            #pragma unroll
            for (int j = 0; j < 4; ++j)
                bfr[j] = *(const short8*)(&Bs[(wn*64 + j*16 + col) * LDSS + kk + quad*8]);
            #pragma unroll
            for (int i = 0; i < 4; ++i)
                #pragma unroll
                for (int j = 0; j < 4; ++j)
                    acc[i][j] = __builtin_amdgcn_mfma_f32_16x16x32_bf16(af[i], bfr[j], acc[i][j], 0, 0, 0);
        }
    }

    // fused epilogue: relu + dot with v, reduce over this block's 128 cols
    float u4[4], v4[4]; int h4[4];
    #pragma unroll
    for (int j = 0; j < 4; ++j) {
        int h = n0 + wn*64 + j*16 + col;
        h4[j] = h; u4[j] = uw[h]; v4[j] = vv[h];
    }
    #pragma unroll
    for (int i = 0; i < 4; ++i) {
        #pragma unroll
        for (int r = 0; r < 4; ++r) {
            int mg = m0 + wm*64 + i*16 + quad*4 + r;
            int b = mg & (B_-1), t = mg >> 7;
            float cv = cov[b*T_ + t];
            float s = 0.f;
            #pragma unroll
            for (int j = 0; j < 4; ++j) {
                float val = acc[i][j][r] + A1w[b*H_ + h4[j]] + cv * u4[j];
                val = val > 0.f ? val : 0.f;
                s += val * v4[j];
            }
            #pragma unroll
            for (int off = 1; off < 16; off <<= 1) s += __shfl_xor(s, off, 64);
            if (col == 0) atomicAdd(&sc[mg], s);
        }
    }
}

// ---------------- softmax over T + coverage outputs ----------------
__global__ void attn_softmax(const float* scores, const float* code_cov, const float* ast_cov,
                             float* wsm, float* out) {
    int b = blockIdx.x, which = blockIdx.y;
    const float* sc = scores + (size_t)which * M_;
    const float* cov = which ? ast_cov : code_cov;
    float* wrow = wsm + ((size_t)which * B_ + b) * T_;
    float* w_out   = out + 3840000 + 65536 + (size_t)which * 65536 + b * T_;
    float* cov_out = out + 3840000 + 65536 + 131072 + (size_t)which * 65536 + b * T_;
    int tid = threadIdx.x;
    __shared__ float red[8];
    float v0 = sc[tid * B_ + b];
    float v1 = sc[(tid + 256) * B_ + b];
    float m = fmaxf(v0, v1);
    #pragma unroll
    for (int off = 32; off; off >>= 1) m = fmaxf(m, __shfl_xor(m, off, 64));
    if ((tid & 63) == 0) red[tid >> 6] = m;
    __syncthreads();
    m = fmaxf(fmaxf(red[0], red[1]), fmaxf(red[2], red[3]));
    float e0 = expf(v0 - m), e1 = expf(v1 - m);
    float s = e0 + e1;
    #pragma unroll
    for (int off = 32; off; off >>= 1) s += __shfl_xor(s, off, 64);
    if ((tid & 63) == 0) red[4 + (tid >> 6)] = s;
    __syncthreads();
    float inv = 1.f / (red[4] + red[5] + red[6] + red[7]);
    float w0 = e0 * inv, w1 = e1 * inv;
    wrow[tid] = w0; wrow[tid + 256] = w1;
    w_out[tid] = w0; w_out[tid + 256] = w1;
    cov_out[tid]       = cov[b*T_ + tid]       + w0;
    cov_out[tid + 256] = cov[b*T_ + tid + 256] + w1;
}

// ---------------- context: ctx[b,h] = 0.5*sum_t (wc*code + wa*ast) ----------------
__global__ void ctx_kernel(const float* code_enc, const float* ast_enc,
                           const float* wsm, float* x) {
    int b = blockIdx.x, tc = blockIdx.y;
    int tid = threadIdx.x;
    __shared__ float wc[128], wa[128];
    if (tid < 128) {
        wc[tid] = wsm[(size_t)b * T_ + tc*128 + tid];
        wa[tid] = wsm[(size_t)(B_ + b) * T_ + tc*128 + tid];
    }
    __syncthreads();
    float a0 = 0.f, a1 = 0.f;
    for (int i = 0; i < 128; ++i) {
        int t = tc * 128 + i;
        float2 c2 = *(const float2*)(code_enc + (size_t)t * (B_*H_) + b*H_ + tid*2);
        float2 a2 = *(const float2*)(ast_enc  + (size_t)t * (B_*H_) + b*H_ + tid*2);
        a0 += wc[i]*c2.x + wa[i]*a2.x;
        a1 += wc[i]*c2.y + wa[i]*a2.y;
    }
    atomicAdd(&x[b*1024 + 512 + tid*2],     0.5f*a0);
    atomicAdd(&x[b*1024 + 512 + tid*2 + 1], 0.5f*a1);
}

// ---------------- GRU gate GEMMs ----------------
__global__ void gru_gemm(const float* x, const float* h0, const float* Wih, const float* Whh,
                         const float* bih, const float* bhh, float* g) {
    int blk = blockIdx.x;
    int b = blk / 6, c = blk % 6;
    int tid = threadIdx.x;
    __shared__ float xs[1024];
    __shared__ float hs[512];
    for (int k = tid; k < 1024; k += 256) xs[k] = x[b*1024 + k];
    for (int k = tid; k < 512; k += 256)  hs[k] = h0[b*512 + k];
    __syncthreads();
    int n = c*256 + tid;
    const float* wi = Wih + (size_t)n * 1024;
    const float* wh = Whh + (size_t)n * 512;
    float si = 0.f, sh = 0.f;
    for (int k = 0; k < 1024; k += 4) {
        float4 w = *(const float4*)(wi + k);
        si += xs[k]*w.x + xs[k+1]*w.y + xs[k+2]*w.z + xs[k+3]*w.w;
    }
    for (int k = 0; k < 512; k += 4) {
        float4 w = *(const float4*)(wh + k);
        sh += hs[k]*w.x + hs[k+1]*w.y + hs[k+2]*w.z + hs[k+3]*w.w;
    }
    si += bih[n]; sh += bhh[n];
    int gate = n >> 9, h = n & 511;
    if (gate == 0)      g[b*512 + h] = si + sh;            // r pre-act
    else if (gate == 1) g[65536 + b*512 + h] = si + sh;    // z pre-act
    else { g[131072 + b*512 + h] = si;                     // i_n
           g[196608 + b*512 + h] = sh; }                   // h_n
}

__global__ void gru_finish(const float* g, const float* x, const float* h0,
                           float* out, float* y) {
    int i = blockIdx.x * 256 + threadIdx.x;   // 0..65535
    int b = i >> 9, h = i & 511;
    float r = 1.f / (1.f + expf(-g[i]));
    float z = 1.f / (1.f + expf(-g[65536 + i]));
    float nn = tanhf(g[131072 + i] + r * g[196608 + i]);
    float h1 = (1.f - z) * nn + z * h0[i];
    out[3840000 + i] = h1;
    y[b*1024 + h]       = h1;
    y[b*1024 + 512 + h] = x[b*1024 + 512 + h];
}

// ---------------- logits GEMM: [128,1024] @ W_out[30000,1024]^T + b_out ----------------
__global__ __launch_bounds__(256)
void logits_gemm(const float* y, const float* Wout, const float* bout, float* out0) {
    int n0 = blockIdx.x * 128;
    __shared__ __align__(16) ushort As[128 * LDSS];
    __shared__ __align__(16) ushort Bs[128 * LDSS];
    int tid = threadIdx.x, lane = tid & 63, wave = tid >> 6;
    int wm = wave >> 1, wn = wave & 1;
    int col = lane & 15, quad = lane >> 4;
    f32x4 acc[4][4];
    #pragma unroll
    for (int i = 0; i < 4; ++i)
        #pragma unroll
        for (int j = 0; j < 4; ++j) acc[i][j] = (f32x4)(0.f);

    for (int k0 = 0; k0 < 1024; k0 += BK) {
        __syncthreads();
        #pragma unroll
        for (int it = 0; it < 4; ++it) {
            int c = it * 256 + tid;
            int row = c >> 3, c8 = (c & 7) * 8;
            *(short8*)(&As[row * LDSS + c8]) =
                cvt8(y + (size_t)row * 1024 + k0 + c8);
            int brow = n0 + row; if (brow > VOUT-1) brow = VOUT-1;
            *(short8*)(&Bs[row * LDSS + c8]) =
                cvt8(Wout + (size_t)brow * 1024 + k0 + c8);
        }
        __syncthreads();
        #pragma unroll
        for (int kk = 0; kk < BK; kk += 32) {
            short8 af[4], bfr[4];
            #pragma unroll
            for (int i = 0; i < 4; ++i)
                af[i] = *(const short8*)(&As[(wm*64 + i*16 + col) * LDSS + kk + quad*8]);
            #pragma unroll
            for (int j = 0; j < 4; ++j)
                bfr[j] = *(const short8*)(&Bs[(wn*64 + j*16 + col) * LDSS + kk + quad*8]);
            #pragma unroll
            for (int i = 0; i < 4; ++i)
                #pragma unroll
                for (int j = 0; j < 4; ++j)
                    acc[i][j] = __builtin_amdgcn_mfma_f32_16x16x32_bf16(af[i], bfr[j], acc[i][j], 0, 0, 0);
        }
    }
    #pragma unroll
    for (int i = 0; i < 4; ++i)
        #pragma unroll
        for (int j = 0; j < 4; ++j) {
            int h = n0 + wn*64 + j*16 + col;
            if (h < VOUT) {
                float bo = bout[h];
                #pragma unroll
                for (int r = 0; r < 4; ++r) {
                    int m = wm*64 + i*16 + quad*4 + r;
                    out0[(size_t)m * VOUT + h] = acc[i][j][r] + bo;
                }
            }
        }
}

__global__ void logsoftmax(float* out0) {
    int b = blockIdx.x; int tid = threadIdx.x;
    float* row = out0 + (size_t)b * VOUT;
    __shared__ float red[8];
    float m = -1e30f;
    for (int i = tid; i < VOUT; i += 256) m = fmaxf(m, row[i]);
    #pragma unroll
    for (int off = 32; off; off >>= 1) m = fmaxf(m, __shfl_xor(m, off, 64));
    if ((tid & 63) == 0) red[tid >> 6] = m;
    __syncthreads();
    m = fmaxf(fmaxf(red[0], red[1]), fmaxf(red[2], red[3]));
    float s = 0.f;
    for (int i = tid; i < VOUT; i += 256) s += expf(row[i] - m);
    #pragma unroll
    for (int off = 32; off; off >>= 1) s += __shfl_xor(s, off, 64);
    if ((tid & 63) == 0) red[4 + (tid >> 6)] = s;
    __syncthreads();
    float lse = m + logf(red[4] + red[5] + red[6] + red[7]);
    for (int i = tid; i < VOUT; i += 256) row[i] = row[i] - lse;
}

// ---------------- launch ----------------
extern "C" void kernel_launch(void* const* d_in, const int* in_sizes, int n_in,
                              void* d_out, int out_size, void* d_ws, size_t ws_size,
                              hipStream_t stream) {
    const int*   inputs   = (const int*)d_in[0];
    const float* h0       = (const float*)d_in[1];
    const float* code_enc = (const float*)d_in[2];
    const float* ast_enc  = (const float*)d_in[3];
    const float* code_cov = (const float*)d_in[4];
    const float* ast_cov  = (const float*)d_in[5];
    const float* emb      = (const float*)d_in[6];
    const float* code_W   = (const float*)d_in[7];
    const float* code_b   = (const float*)d_in[8];
    const float* code_v   = (const float*)d_in[9];
    const float* code_Wc  = (const float*)d_in[10];
    const float* ast_W    = (const float*)d_in[11];
    const float* ast_b    = (const float*)d_in[12];
    const float* ast_v    = (const float*)d_in[13];
    const float* ast_Wc   = (const float*)d_in[14];
    const float* gru_Wih  = (const float*)d_in[15];
    const float* gru_Whh  = (const float*)d_in[16];
    const float* gru_bih  = (const float*)d_in[17];
    const float* gru_bhh  = (const float*)d_in[18];
    const float* W_out    = (const float*)d_in[19];
    const float* b_out    = (const float*)d_in[20];
    float* out = (float*)d_out;

    // workspace layout — 3.51 MB total
    char* ws = (char*)d_ws;
    float* scores = (float*)(ws + 0);          // 2*65536 f32   = 512 KB  (zeroed)
    float* x      = (float*)(ws + 524288);     // 128*1024 f32  = 512 KB  (zeroed; [.,512:) = ctx acc)
    float* A1     = (float*)(ws + 1048576);    // 2*128*512 f32 = 512 KB
    float* wsm    = (float*)(ws + 1572864);    // 2*128*512 f32 = 512 KB
    float* u      = (float*)(ws + 2097152);    // 2*512 f32     = 4 KB
    float* g      = (float*)(ws + 2101248);    // 4*128*512 f32 = 1 MB
    float* y      = (float*)(ws + 3149824);    // 128*1024 f32  = 512 KB

    hipMemsetAsync(ws, 0, 1048576, stream);    // zero scores + x

    emb_gather<<<dim3(B_), dim3(256), 0, stream>>>(inputs, emb, x);
    prep_a1<<<dim3(B_, 2), dim3(256), 0, stream>>>(h0, code_W, code_b, ast_W, ast_b, A1);
    prep_u<<<dim3(2), dim3(512), 0, stream>>>(code_Wc, code_W, ast_Wc, ast_W, u);

    attn_gemm<<<dim3(2048, 2), dim3(256), 0, stream>>>(
        code_enc, ast_enc, code_W, ast_W, code_v, ast_v, code_cov, ast_cov, A1, u, scores);

    attn_softmax<<<dim3(B_, 2), dim3(256), 0, stream>>>(scores, code_cov, ast_cov, wsm, out);

    ctx_kernel<<<dim3(B_, 4), dim3(256), 0, stream>>>(code_enc, ast_enc, wsm, x);

    gru_gemm<<<dim3(768), dim3(256), 0, stream>>>(x, h0, gru_Wih, gru_Whh, gru_bih, gru_bhh, g);
    gru_finish<<<dim3(256), dim3(256), 0, stream>>>(g, x, h0, out, y);

    logits_gemm<<<dim3(235), dim3(256), 0, stream>>>(y, W_out, b_out, out);
    logsoftmax<<<dim3(B_), dim3(256), 0, stream>>>(out);
}

// Round 3
// 857.703 us; speedup vs baseline: 1.2268x; 1.1139x over previous
//
#include <hip/hip_runtime.h>
#include <math.h>

#define B_ 128
#define T_ 512
#define H_ 512
#define E_ 512
#define VOUT 30000
#define M_ (T_*B_)

typedef __attribute__((ext_vector_type(8))) short short8;
typedef __attribute__((ext_vector_type(4))) float f32x4;

// convert two float4 (8 consecutive f32) to bf16x8 via HW packed converts (RNE)
__device__ __forceinline__ short8 cvt8v(float4 a, float4 b) {
    unsigned int r0, r1, r2, r3;
    asm("v_cvt_pk_bf16_f32 %0, %1, %2" : "=v"(r0) : "v"(a.x), "v"(a.y));
    asm("v_cvt_pk_bf16_f32 %0, %1, %2" : "=v"(r1) : "v"(a.z), "v"(a.w));
    asm("v_cvt_pk_bf16_f32 %0, %1, %2" : "=v"(r2) : "v"(b.x), "v"(b.y));
    asm("v_cvt_pk_bf16_f32 %0, %1, %2" : "=v"(r3) : "v"(b.z), "v"(b.w));
    union { unsigned int u[4]; short8 s; } u;
    u.u[0] = r0; u.u[1] = r1; u.u[2] = r2; u.u[3] = r3;
    return u.s;
}
__device__ __forceinline__ short8 cvt8(const float* p) {
    return cvt8v(*(const float4*)p, *(const float4*)(p + 4));
}

// ---------------- small prep kernels ----------------

__global__ void emb_gather(const int* idx, const float* emb, float* x) {
    int b = blockIdx.x; int t = threadIdx.x;
    int row = idx[b];
    x[b*1024 + t]       = emb[(size_t)row*E_ + t];
    x[b*1024 + t + 256] = emb[(size_t)row*E_ + t + 256];
}

// A1[which][b][h] = sum_k h0[b,k]*W[h,k] + b_attn[h]
// block = 64 h-rows x 16 b (h0 staged in LDS); W read ~8x total instead of 128x.
__global__ void prep_a1(const float* h0, const float* Wc, const float* bc_,
                        const float* Wa, const float* ba, float* A1) {
    int hc = blockIdx.x;          // 0..7  -> h0r = hc*64
    int bcb = blockIdx.y;         // 0..7  -> b0 = bcb*16
    int which = blockIdx.z;
    const float* W    = which ? Wa : Wc;
    const float* bias = which ? ba : bc_;
    int b0 = bcb * 16;
    int tid = threadIdx.x;
    __shared__ float hs[16][512];   // 32 KB
    for (int idx = tid; idx < 2048; idx += 256) {
        int row = idx >> 7, c = (idx & 127) * 4;
        *(float4*)&hs[row][c] = *(const float4*)(h0 + (size_t)(b0+row)*512 + c);
    }
    __syncthreads();
    int h = hc*64 + (tid & 63);
    int r = (tid >> 6) * 4;        // 4 b's per thread
    const float* Wr = W + (size_t)h * 1536;
    float a0=0.f, a1=0.f, a2=0.f, a3=0.f;
    for (int k = 0; k < 512; k += 4) {
        float4 w  = *(const float4*)(Wr + k);
        float4 x0 = *(const float4*)&hs[r][k];
        float4 x1 = *(const float4*)&hs[r+1][k];
        float4 x2 = *(const float4*)&hs[r+2][k];
        float4 x3 = *(const float4*)&hs[r+3][k];
        a0 += w.x*x0.x + w.y*x0.y + w.z*x0.z + w.w*x0.w;
        a1 += w.x*x1.x + w.y*x1.y + w.z*x1.z + w.w*x1.w;
        a2 += w.x*x2.x + w.y*x2.y + w.z*x2.z + w.w*x2.w;
        a3 += w.x*x3.x + w.y*x3.y + w.z*x3.z + w.w*x3.w;
    }
    float bb = bias[h];
    A1[((size_t)which*B_ + (b0+r  ))*H_ + h] = a0 + bb;
    A1[((size_t)which*B_ + (b0+r+1))*H_ + h] = a1 + bb;
    A1[((size_t)which*B_ + (b0+r+2))*H_ + h] = a2 + bb;
    A1[((size_t)which*B_ + (b0+r+3))*H_ + h] = a3 + bb;
}

// u[which][h] = sum_k Wcov[k] * W[h, 1024+k]
__global__ void prep_u(const float* wcov_c, const float* W_c,
                       const float* wcov_a, const float* W_a, float* u) {
    int which = blockIdx.x; int h = threadIdx.x;
    const float* W  = which ? W_a : W_c;
    const float* wc = which ? wcov_a : wcov_c;
    const float* Wr = W + (size_t)h*1536 + 1024;
    float s = 0.f;
    for (int k = 0; k < H_; ++k) s += wc[k] * Wr[k];
    u[which*H_ + h] = s;
}

// ---------------- attention GEMM (full-N block, fused score epilogue) ----------------
// scores[which][b][t] = sum_h relu( enc@W2^T + A1[b,h] + cov[b,t]*u[h] ) * v[h]
// block: 1024 threads = 16 waves (2 m-halves x 8 n-slices); tile 128m x 512n (all h).
// m0 = mt*128 -> one t = mt, b = 0..127 per block. enc converted exactly once.

#define BK 64
#define LDSS 72   // padded LDS row stride (elements)

__global__ __launch_bounds__(1024)
void attn_gemm(const float* code_enc, const float* ast_enc,
               const float* code_W, const float* ast_W,
               const float* code_v, const float* ast_v,
               const float* code_cov, const float* ast_cov,
               const float* A1, const float* u, float* scores) {
    int which = blockIdx.y;
    const float* enc = which ? ast_enc : code_enc;
    const float* W   = which ? ast_W   : code_W;
    const float* vv  = which ? ast_v   : code_v;
    const float* cov = which ? ast_cov : code_cov;
    const float* A1w = A1 + (size_t)which * B_ * H_;
    const float* uw  = u + which * H_;
    float* sc = scores + (size_t)which * M_;

    // XCD-chunked swizzle (512 blocks, bijective)
    int bid = blockIdx.x;
    int mt  = ((bid & 7) << 6) + (bid >> 3);
    int m0  = mt * 128;                      // t = mt, rows = b

    __shared__ __align__(16) ushort As[128 * LDSS];   // 18.4 KB
    __shared__ __align__(16) ushort Bs[512 * LDSS];   // 73.7 KB
    __shared__ float red[128][8];                     // 4 KB

    int tid = threadIdx.x;
    int lane = tid & 63, wave = tid >> 6;
    int wm2 = wave >> 3, wn8 = wave & 7;     // m-half, n-slice
    int col = lane & 15, quad = lane >> 4;

    // staging: As 8192 elems -> 1 short8/thread; Bs 32768 -> 4 short8/thread
    int arow = tid >> 3, ac8 = (tid & 7) * 8;
    const float* asrc = enc + (size_t)(m0 + arow) * H_ + ac8;
    const float* bsrc = W + (size_t)arow * 1536 + 512 + ac8;   // + it*128*1536 + k0

    f32x4 acc[4][4];
    #pragma unroll
    for (int i = 0; i < 4; ++i)
        #pragma unroll
        for (int j = 0; j < 4; ++j) acc[i][j] = (f32x4)(0.f);

    // prologue: prefetch K-tile 0 into registers
    float4 ra0, ra1, rb[8];
    ra0 = *(const float4*)(asrc);
    ra1 = *(const float4*)(asrc + 4);
    #pragma unroll
    for (int it = 0; it < 4; ++it) {
        const float* p = bsrc + (size_t)it * 196608;
        rb[2*it]   = *(const float4*)(p);
        rb[2*it+1] = *(const float4*)(p + 4);
    }

    for (int kt = 0; kt < 8; ++kt) {
        __syncthreads();    // previous tile's MFMA done reading LDS
        *(short8*)(&As[arow * LDSS + ac8]) = cvt8v(ra0, ra1);
        #pragma unroll
        for (int it = 0; it < 4; ++it)
            *(short8*)(&Bs[(it*128 + arow) * LDSS + ac8]) = cvt8v(rb[2*it], rb[2*it+1]);
        __syncthreads();
        if (kt < 7) {       // issue next tile's loads before MFMA (latency hidden)
            int k0 = (kt + 1) * BK;
            ra0 = *(const float4*)(asrc + k0);
            ra1 = *(const float4*)(asrc + k0 + 4);
            #pragma unroll
            for (int it = 0; it < 4; ++it) {
                const float* p = bsrc + (size_t)it * 196608 + k0;
                rb[2*it]   = *(const float4*)(p);
                rb[2*it+1] = *(const float4*)(p + 4);
            }
        }
        #pragma unroll
        for (int kk = 0; kk < BK; kk += 32) {
            short8 af[4], bfr[4];
            #pragma unroll
            for (int i = 0; i < 4; ++i)
                af[i] = *(const short8*)(&As[(wm2*64 + i*16 + col) * LDSS + kk + quad*8]);
            #pragma unroll
            for (int j = 0; j < 4; ++j)
                bfr[j] = *(const short8*)(&Bs[(wn8*64 + j*16 + col) * LDSS + kk + quad*8]);
            #pragma unroll
            for (int i = 0; i < 4; ++i)
                #pragma unroll
                for (int j = 0; j < 4; ++j)
                    acc[i][j] = __builtin_amdgcn_mfma_f32_16x16x32_bf16(af[i], bfr[j], acc[i][j], 0, 0, 0);
        }
    }

    // fused epilogue: relu + dot with v over this wave's 64 cols, LDS-reduce 8 slices
    float u4[4], v4[4]; int h4[4];
    #pragma unroll
    for (int j = 0; j < 4; ++j) {
        int h = wn8*64 + j*16 + col;
        h4[j] = h; u4[j] = uw[h]; v4[j] = vv[h];
    }
    #pragma unroll
    for (int i = 0; i < 4; ++i) {
        #pragma unroll
        for (int r = 0; r < 4; ++r) {
            int b = wm2*64 + i*16 + quad*4 + r;     // block-local row = batch index
            float cv = cov[b*T_ + mt];
            float s = 0.f;
            #pragma unroll
            for (int j = 0; j < 4; ++j) {
                float val = acc[i][j][r] + A1w[b*H_ + h4[j]] + cv * u4[j];
                val = val > 0.f ? val : 0.f;
                s += val * v4[j];
            }
            #pragma unroll
            for (int off = 1; off < 16; off <<= 1) s += __shfl_xor(s, off, 64);
            if (col == 0) red[b][wn8] = s;
        }
    }
    __syncthreads();
    if (tid < 128) {
        float s = 0.f;
        #pragma unroll
        for (int w = 0; w < 8; ++w) s += red[tid][w];
        sc[(size_t)tid * T_ + mt] = s;    // [b][t] layout
    }
}

// ---------------- softmax over T + coverage outputs (contiguous reads now) ----------------
__global__ void attn_softmax(const float* scores, const float* code_cov, const float* ast_cov,
                             float* wsm, float* out) {
    int b = blockIdx.x, which = blockIdx.y;
    const float* sc = scores + (size_t)which * M_ + (size_t)b * T_;
    const float* cov = which ? ast_cov : code_cov;
    float* wrow = wsm + ((size_t)which * B_ + b) * T_;
    float* w_out   = out + 3840000 + 65536 + (size_t)which * 65536 + b * T_;
    float* cov_out = out + 3840000 + 65536 + 131072 + (size_t)which * 65536 + b * T_;
    int tid = threadIdx.x;
    __shared__ float red[8];
    float v0 = sc[tid];
    float v1 = sc[tid + 256];
    float m = fmaxf(v0, v1);
    #pragma unroll
    for (int off = 32; off; off >>= 1) m = fmaxf(m, __shfl_xor(m, off, 64));
    if ((tid & 63) == 0) red[tid >> 6] = m;
    __syncthreads();
    m = fmaxf(fmaxf(red[0], red[1]), fmaxf(red[2], red[3]));
    float e0 = expf(v0 - m), e1 = expf(v1 - m);
    float s = e0 + e1;
    #pragma unroll
    for (int off = 32; off; off >>= 1) s += __shfl_xor(s, off, 64);
    if ((tid & 63) == 0) red[4 + (tid >> 6)] = s;
    __syncthreads();
    float inv = 1.f / (red[4] + red[5] + red[6] + red[7]);
    float w0 = e0 * inv, w1 = e1 * inv;
    wrow[tid] = w0; wrow[tid + 256] = w1;
    w_out[tid] = w0; w_out[tid + 256] = w1;
    cov_out[tid]       = cov[b*T_ + tid]       + w0;
    cov_out[tid + 256] = cov[b*T_ + tid + 256] + w1;
}

// ---------------- context: ctx[b,h] = 0.5*sum_t (wc*code + wa*ast) ----------------
__global__ void ctx_kernel(const float* code_enc, const float* ast_enc,
                           const float* wsm, float* x) {
    int b = blockIdx.x, tc = blockIdx.y;     // tc 0..7
    int tid = threadIdx.x;                   // 0..127
    __shared__ float wc[64], wa[64];
    if (tid < 64) {
        wc[tid] = wsm[(size_t)b * T_ + tc*64 + tid];
        wa[tid] = wsm[(size_t)(B_ + b) * T_ + tc*64 + tid];
    }
    __syncthreads();
    float a0=0.f, a1=0.f, a2=0.f, a3=0.f;
    for (int i = 0; i < 64; ++i) {
        int t = tc * 64 + i;
        float4 c4 = *(const float4*)(code_enc + (size_t)t * (B_*H_) + b*H_ + tid*4);
        float4 a4 = *(const float4*)(ast_enc  + (size_t)t * (B_*H_) + b*H_ + tid*4);
        a0 += wc[i]*c4.x + wa[i]*a4.x;
        a1 += wc[i]*c4.y + wa[i]*a4.y;
        a2 += wc[i]*c4.z + wa[i]*a4.z;
        a3 += wc[i]*c4.w + wa[i]*a4.w;
    }
    atomicAdd(&x[b*1024 + 512 + tid*4],     0.5f*a0);
    atomicAdd(&x[b*1024 + 512 + tid*4 + 1], 0.5f*a1);
    atomicAdd(&x[b*1024 + 512 + tid*4 + 2], 0.5f*a2);
    atomicAdd(&x[b*1024 + 512 + tid*4 + 3], 0.5f*a3);
}

// ---------------- GRU gate GEMMs ----------------
// block = 64 n-rows x 8 b (x/h staged in LDS); weights read ~16x total instead of 128x.
__global__ void gru_gemm(const float* x, const float* h0, const float* Wih, const float* Whh,
                         const float* bih, const float* bhh, float* g) {
    int nc = blockIdx.x;          // 0..23
    int bcb = blockIdx.y;         // 0..15
    int b0 = bcb * 8;
    int tid = threadIdx.x;
    __shared__ float xs[8][1024];   // 32 KB
    __shared__ float hs[8][512];    // 16 KB
    for (int idx = tid; idx < 2048; idx += 256) {
        int row = idx >> 8, c = (idx & 255) * 4;
        *(float4*)&xs[row][c] = *(const float4*)(x + (size_t)(b0+row)*1024 + c);
    }
    for (int idx = tid; idx < 1024; idx += 256) {
        int row = idx >> 7, c = (idx & 127) * 4;
        *(float4*)&hs[row][c] = *(const float4*)(h0 + (size_t)(b0+row)*512 + c);
    }
    __syncthreads();
    int n = nc * 64 + (tid & 63);
    int r0 = (tid >> 6) * 2, r1 = r0 + 1;   // 2 b's per thread
    const float* wi = Wih + (size_t)n * 1024;
    const float* wh = Whh + (size_t)n * 512;
    float si0=0.f, si1=0.f, sh0=0.f, sh1=0.f;
    for (int k = 0; k < 1024; k += 4) {
        float4 w  = *(const float4*)(wi + k);
        float4 x0 = *(const float4*)&xs[r0][k];
        float4 x1 = *(const float4*)&xs[r1][k];
        si0 += w.x*x0.x + w.y*x0.y + w.z*x0.z + w.w*x0.w;
        si1 += w.x*x1.x + w.y*x1.y + w.z*x1.z + w.w*x1.w;
    }
    for (int k = 0; k < 512; k += 4) {
        float4 w  = *(const float4*)(wh + k);
        float4 x0 = *(const float4*)&hs[r0][k];
        float4 x1 = *(const float4*)&hs[r1][k];
        sh0 += w.x*x0.x + w.y*x0.y + w.z*x0.z + w.w*x0.w;
        sh1 += w.x*x1.x + w.y*x1.y + w.z*x1.z + w.w*x1.w;
    }
    int gate = n >> 9, h = n & 511;
    float bi = bih[n], bh = bhh[n];
    int b;
    b = b0 + r0;
    {
        float A = si0 + bi, Bv = sh0 + bh;
        if (gate == 0)      g[b*512 + h] = A + Bv;
        else if (gate == 1) g[65536 + b*512 + h] = A + Bv;
        else { g[131072 + b*512 + h] = A; g[196608 + b*512 + h] = Bv; }
    }
    b = b0 + r1;
    {
        float A = si1 + bi, Bv = sh1 + bh;
        if (gate == 0)      g[b*512 + h] = A + Bv;
        else if (gate == 1) g[65536 + b*512 + h] = A + Bv;
        else { g[131072 + b*512 + h] = A; g[196608 + b*512 + h] = Bv; }
    }
}

__global__ void gru_finish(const float* g, const float* x, const float* h0,
                           float* out, float* y) {
    int i = blockIdx.x * 256 + threadIdx.x;   // 0..65535
    int b = i >> 9, h = i & 511;
    float r = 1.f / (1.f + expf(-g[i]));
    float z = 1.f / (1.f + expf(-g[65536 + i]));
    float nn = tanhf(g[131072 + i] + r * g[196608 + i]);
    float h1 = (1.f - z) * nn + z * h0[i];
    out[3840000 + i] = h1;
    y[b*1024 + h]       = h1;
    y[b*1024 + 512 + h] = x[b*1024 + 512 + h];
}

// ---------------- logits GEMM: [128,1024] @ W_out[30000,1024]^T + b_out ----------------
__global__ __launch_bounds__(256)
void logits_gemm(const float* y, const float* Wout, const float* bout, float* out0) {
    int n0 = blockIdx.x * 128;
    __shared__ __align__(16) ushort As[128 * LDSS];
    __shared__ __align__(16) ushort Bs[128 * LDSS];
    int tid = threadIdx.x, lane = tid & 63, wave = tid >> 6;
    int wm = wave >> 1, wn = wave & 1;
    int col = lane & 15, quad = lane >> 4;
    f32x4 acc[4][4];
    #pragma unroll
    for (int i = 0; i < 4; ++i)
        #pragma unroll
        for (int j = 0; j < 4; ++j) acc[i][j] = (f32x4)(0.f);

    for (int k0 = 0; k0 < 1024; k0 += BK) {
        __syncthreads();
        #pragma unroll
        for (int it = 0; it < 4; ++it) {
            int c = it * 256 + tid;
            int row = c >> 3, c8 = (c & 7) * 8;
            *(short8*)(&As[row * LDSS + c8]) =
                cvt8(y + (size_t)row * 1024 + k0 + c8);
            int brow = n0 + row; if (brow > VOUT-1) brow = VOUT-1;
            *(short8*)(&Bs[row * LDSS + c8]) =
                cvt8(Wout + (size_t)brow * 1024 + k0 + c8);
        }
        __syncthreads();
        #pragma unroll
        for (int kk = 0; kk < BK; kk += 32) {
            short8 af[4], bfr[4];
            #pragma unroll
            for (int i = 0; i < 4; ++i)
                af[i] = *(const short8*)(&As[(wm*64 + i*16 + col) * LDSS + kk + quad*8]);
            #pragma unroll
            for (int j = 0; j < 4; ++j)
                bfr[j] = *(const short8*)(&Bs[(wn*64 + j*16 + col) * LDSS + kk + quad*8]);
            #pragma unroll
            for (int i = 0; i < 4; ++i)
                #pragma unroll
                for (int j = 0; j < 4; ++j)
                    acc[i][j] = __builtin_amdgcn_mfma_f32_16x16x32_bf16(af[i], bfr[j], acc[i][j], 0, 0, 0);
        }
    }
    #pragma unroll
    for (int i = 0; i < 4; ++i)
        #pragma unroll
        for (int j = 0; j < 4; ++j) {
            int h = n0 + wn*64 + j*16 + col;
            if (h < VOUT) {
                float bo = bout[h];
                #pragma unroll
                for (int r = 0; r < 4; ++r) {
                    int m = wm*64 + i*16 + quad*4 + r;
                    out0[(size_t)m * VOUT + h] = acc[i][j][r] + bo;
                }
            }
        }
}

__global__ void logsoftmax(float* out0) {
    int b = blockIdx.x; int tid = threadIdx.x;
    float* row = out0 + (size_t)b * VOUT;
    __shared__ float red[8];
    float m = -1e30f;
    for (int i = tid; i < VOUT; i += 256) m = fmaxf(m, row[i]);
    #pragma unroll
    for (int off = 32; off; off >>= 1) m = fmaxf(m, __shfl_xor(m, off, 64));
    if ((tid & 63) == 0) red[tid >> 6] = m;
    __syncthreads();
    m = fmaxf(fmaxf(red[0], red[1]), fmaxf(red[2], red[3]));
    float s = 0.f;
    for (int i = tid; i < VOUT; i += 256) s += expf(row[i] - m);
    #pragma unroll
    for (int off = 32; off; off >>= 1) s += __shfl_xor(s, off, 64);
    if ((tid & 63) == 0) red[4 + (tid >> 6)] = s;
    __syncthreads();
    float lse = m + logf(red[4] + red[5] + red[6] + red[7]);
    for (int i = tid; i < VOUT; i += 256) row[i] = row[i] - lse;
}

// ---------------- launch ----------------
extern "C" void kernel_launch(void* const* d_in, const int* in_sizes, int n_in,
                              void* d_out, int out_size, void* d_ws, size_t ws_size,
                              hipStream_t stream) {
    const int*   inputs   = (const int*)d_in[0];
    const float* h0       = (const float*)d_in[1];
    const float* code_enc = (const float*)d_in[2];
    const float* ast_enc  = (const float*)d_in[3];
    const float* code_cov = (const float*)d_in[4];
    const float* ast_cov  = (const float*)d_in[5];
    const float* emb      = (const float*)d_in[6];
    const float* code_W   = (const float*)d_in[7];
    const float* code_b   = (const float*)d_in[8];
    const float* code_v   = (const float*)d_in[9];
    const float* code_Wc  = (const float*)d_in[10];
    const float* ast_W    = (const float*)d_in[11];
    const float* ast_b    = (const float*)d_in[12];
    const float* ast_v    = (const float*)d_in[13];
    const float* ast_Wc   = (const float*)d_in[14];
    const float* gru_Wih  = (const float*)d_in[15];
    const float* gru_Whh  = (const float*)d_in[16];
    const float* gru_bih  = (const float*)d_in[17];
    const float* gru_bhh  = (const float*)d_in[18];
    const float* W_out    = (const float*)d_in[19];
    const float* b_out    = (const float*)d_in[20];
    float* out = (float*)d_out;

    // workspace layout — 3.51 MB total
    char* ws = (char*)d_ws;
    float* scores = (float*)(ws + 0);          // 2*65536 f32   = 512 KB  ([which][b][t], fully written)
    float* x      = (float*)(ws + 524288);     // 128*1024 f32  = 512 KB  (zeroed; [.,512:) = ctx acc)
    float* A1     = (float*)(ws + 1048576);    // 2*128*512 f32 = 512 KB
    float* wsm    = (float*)(ws + 1572864);    // 2*128*512 f32 = 512 KB
    float* u      = (float*)(ws + 2097152);    // 2*512 f32     = 4 KB
    float* g      = (float*)(ws + 2101248);    // 4*128*512 f32 = 1 MB
    float* y      = (float*)(ws + 3149824);    // 128*1024 f32  = 512 KB

    hipMemsetAsync(ws + 524288, 0, 524288, stream);    // zero x only (scores no longer atomic)

    emb_gather<<<dim3(B_), dim3(256), 0, stream>>>(inputs, emb, x);
    prep_a1<<<dim3(8, 8, 2), dim3(256), 0, stream>>>(h0, code_W, code_b, ast_W, ast_b, A1);
    prep_u<<<dim3(2), dim3(512), 0, stream>>>(code_Wc, code_W, ast_Wc, ast_W, u);

    attn_gemm<<<dim3(512, 2), dim3(1024), 0, stream>>>(
        code_enc, ast_enc, code_W, ast_W, code_v, ast_v, code_cov, ast_cov, A1, u, scores);

    attn_softmax<<<dim3(B_, 2), dim3(256), 0, stream>>>(scores, code_cov, ast_cov, wsm, out);

    ctx_kernel<<<dim3(B_, 8), dim3(128), 0, stream>>>(code_enc, ast_enc, wsm, x);

    gru_gemm<<<dim3(24, 16), dim3(256), 0, stream>>>(x, h0, gru_Wih, gru_Whh, gru_bih, gru_bhh, g);
    gru_finish<<<dim3(256), dim3(256), 0, stream>>>(g, x, h0, out, y);

    logits_gemm<<<dim3(235), dim3(256), 0, stream>>>(y, W_out, b_out, out);
    logsoftmax<<<dim3(B_), dim3(256), 0, stream>>>(out);
}

// Round 4
// 824.618 us; speedup vs baseline: 1.2760x; 1.0401x over previous
//
#include <hip/hip_runtime.h>
#include <math.h>

#define B_ 128
#define T_ 512
#define H_ 512
#define E_ 512
#define VOUT 30000
#define M_ (T_*B_)

typedef __attribute__((ext_vector_type(8))) short short8;
typedef __attribute__((ext_vector_type(4))) float f32x4;

// convert two float4 (8 consecutive f32) to bf16x8 via HW packed converts (RNE)
__device__ __forceinline__ short8 cvt8v(float4 a, float4 b) {
    unsigned int r0, r1, r2, r3;
    asm("v_cvt_pk_bf16_f32 %0, %1, %2" : "=v"(r0) : "v"(a.x), "v"(a.y));
    asm("v_cvt_pk_bf16_f32 %0, %1, %2" : "=v"(r1) : "v"(a.z), "v"(a.w));
    asm("v_cvt_pk_bf16_f32 %0, %1, %2" : "=v"(r2) : "v"(b.x), "v"(b.y));
    asm("v_cvt_pk_bf16_f32 %0, %1, %2" : "=v"(r3) : "v"(b.z), "v"(b.w));
    union { unsigned int u[4]; short8 s; } u;
    u.u[0] = r0; u.u[1] = r1; u.u[2] = r2; u.u[3] = r3;
    return u.s;
}

// ---------------- small prep kernels ----------------

__global__ void emb_gather(const int* idx, const float* emb, float* x) {
    int b = blockIdx.x; int t = threadIdx.x;
    int row = idx[b];
    x[b*1024 + t]       = emb[(size_t)row*E_ + t];
    x[b*1024 + t + 256] = emb[(size_t)row*E_ + t + 256];
}

// A1[which][b][h] = sum_k h0[b,k]*W[h,k] + b_attn[h]
__global__ void prep_a1(const float* h0, const float* Wc, const float* bc_,
                        const float* Wa, const float* ba, float* A1) {
    int hc = blockIdx.x;          // 0..7
    int bcb = blockIdx.y;         // 0..7
    int which = blockIdx.z;
    const float* W    = which ? Wa : Wc;
    const float* bias = which ? ba : bc_;
    int b0 = bcb * 16;
    int tid = threadIdx.x;
    __shared__ float hs[16][512];   // 32 KB
    for (int idx = tid; idx < 2048; idx += 256) {
        int row = idx >> 7, c = (idx & 127) * 4;
        *(float4*)&hs[row][c] = *(const float4*)(h0 + (size_t)(b0+row)*512 + c);
    }
    __syncthreads();
    int h = hc*64 + (tid & 63);
    int r = (tid >> 6) * 4;
    const float* Wr = W + (size_t)h * 1536;
    float a0=0.f, a1=0.f, a2=0.f, a3=0.f;
    for (int k = 0; k < 512; k += 4) {
        float4 w  = *(const float4*)(Wr + k);
        float4 x0 = *(const float4*)&hs[r][k];
        float4 x1 = *(const float4*)&hs[r+1][k];
        float4 x2 = *(const float4*)&hs[r+2][k];
        float4 x3 = *(const float4*)&hs[r+3][k];
        a0 += w.x*x0.x + w.y*x0.y + w.z*x0.z + w.w*x0.w;
        a1 += w.x*x1.x + w.y*x1.y + w.z*x1.z + w.w*x1.w;
        a2 += w.x*x2.x + w.y*x2.y + w.z*x2.z + w.w*x2.w;
        a3 += w.x*x3.x + w.y*x3.y + w.z*x3.z + w.w*x3.w;
    }
    float bb = bias[h];
    A1[((size_t)which*B_ + (b0+r  ))*H_ + h] = a0 + bb;
    A1[((size_t)which*B_ + (b0+r+1))*H_ + h] = a1 + bb;
    A1[((size_t)which*B_ + (b0+r+2))*H_ + h] = a2 + bb;
    A1[((size_t)which*B_ + (b0+r+3))*H_ + h] = a3 + bb;
}

// u[which][h] = sum_k Wcov[k] * W[h, 1024+k]
__global__ void prep_u(const float* wcov_c, const float* W_c,
                       const float* wcov_a, const float* W_a, float* u) {
    int which = blockIdx.x; int h = threadIdx.x;
    const float* W  = which ? W_a : W_c;
    const float* wc = which ? wcov_a : wcov_c;
    const float* Wr = W + (size_t)h*1536 + 1024;
    float s = 0.f;
    for (int k = 0; k < H_; ++k) s += wc[k] * Wr[k];
    u[which*H_ + h] = s;
}

// ---------------- attention GEMM (full-N block, dbuf pipeline, fused epilogue) ----------------
// scores[which][b][t] = sum_h relu( enc@W2^T + A1[b,h] + cov[b,t]*u[h] ) * v[h]
// block: 1024 threads = 16 waves (2 m-halves x 8 n-slices); tile 128m x 512n.
// BK=32, double-buffered LDS, ONE barrier per K-step:
//   cvt+write buf[k&1] -> barrier -> issue loads(k+1) -> MFMA buf[k&1]
// Global latency for tile k+1 hides under tile k's MFMA phase; write phase of
// fast waves overlaps MFMA phase of slow waves (different LDS buffers).

#define ALS 40   // attn LDS row stride (32 + 8 pad), ushorts

__global__ __launch_bounds__(1024)
void attn_gemm(const float* code_enc, const float* ast_enc,
               const float* code_W, const float* ast_W,
               const float* code_v, const float* ast_v,
               const float* code_cov, const float* ast_cov,
               const float* A1, const float* u, float* scores) {
    int which = blockIdx.y;
    const float* enc = which ? ast_enc : code_enc;
    const float* W   = which ? ast_W   : code_W;
    const float* vv  = which ? ast_v   : code_v;
    const float* cov = which ? ast_cov : code_cov;
    const float* A1w = A1 + (size_t)which * B_ * H_;
    const float* uw  = u + which * H_;
    float* sc = scores + (size_t)which * M_;

    // XCD-chunked swizzle (512 blocks, bijective)
    int bid = blockIdx.x;
    int mt  = ((bid & 7) << 6) + (bid >> 3);
    int m0  = mt * 128;                      // t = mt, rows = b

    __shared__ __align__(16) ushort As[2][128 * ALS];   // 20 KB
    __shared__ __align__(16) ushort Bs[2][512 * ALS];   // 80 KB
    __shared__ float red[128][8];                       // 4 KB

    int tid = threadIdx.x;
    int lane = tid & 63, wave = tid >> 6;
    int wm2 = wave >> 3, wn8 = wave & 7;     // m-half, n-slice
    int col = lane & 15, quad = lane >> 4;

    // staging geometry: row = idx>>2, c8 = (idx&3)*8 (8 f32 per idx)
    int srow = tid >> 2, sc8 = (tid & 3) * 8;
    const float* asrc  = enc + (size_t)(m0 + srow) * H_ + sc8;             // tid<512 only
    const float* bsrc0 = W + (size_t)srow * 1536 + 512 + sc8;              // rows 0..255
    const float* bsrc1 = W + (size_t)(256 + srow) * 1536 + 512 + sc8;      // rows 256..511
    ushort* adst = &As[0][srow * ALS + sc8];
    ushort* bdst0 = &Bs[0][srow * ALS + sc8];
    ushort* bdst1 = &Bs[0][(256 + srow) * ALS + sc8];
    const int bufstep_a = 128 * ALS, bufstep_b = 512 * ALS;

    f32x4 acc[4][4];
    #pragma unroll
    for (int i = 0; i < 4; ++i)
        #pragma unroll
        for (int j = 0; j < 4; ++j) acc[i][j] = (f32x4)(0.f);

    // prologue: prefetch K-step 0 into registers
    float4 ra0, ra1, rb0a, rb0b, rb1a, rb1b;
    if (tid < 512) { ra0 = *(const float4*)(asrc); ra1 = *(const float4*)(asrc + 4); }
    rb0a = *(const float4*)(bsrc0); rb0b = *(const float4*)(bsrc0 + 4);
    rb1a = *(const float4*)(bsrc1); rb1b = *(const float4*)(bsrc1 + 4);

    for (int kt = 0; kt < 16; ++kt) {
        int cur = kt & 1;
        // write phase: regs (tile kt) -> LDS buf[cur]
        if (tid < 512) *(short8*)(adst + cur * bufstep_a) = cvt8v(ra0, ra1);
        *(short8*)(bdst0 + cur * bufstep_b) = cvt8v(rb0a, rb0b);
        *(short8*)(bdst1 + cur * bufstep_b) = cvt8v(rb1a, rb1b);
        __syncthreads();
        if (kt < 15) {       // issue next tile's loads; land during MFMA below
            int k0 = (kt + 1) * 32;
            if (tid < 512) { ra0 = *(const float4*)(asrc + k0); ra1 = *(const float4*)(asrc + k0 + 4); }
            rb0a = *(const float4*)(bsrc0 + k0); rb0b = *(const float4*)(bsrc0 + k0 + 4);
            rb1a = *(const float4*)(bsrc1 + k0); rb1b = *(const float4*)(bsrc1 + k0 + 4);
        }
        // MFMA phase on buf[cur]
        short8 af[4], bfr[4];
        #pragma unroll
        for (int i = 0; i < 4; ++i)
            af[i] = *(const short8*)(&As[cur][(wm2*64 + i*16 + col) * ALS + quad*8]);
        #pragma unroll
        for (int j = 0; j < 4; ++j)
            bfr[j] = *(const short8*)(&Bs[cur][(wn8*64 + j*16 + col) * ALS + quad*8]);
        #pragma unroll
        for (int i = 0; i < 4; ++i)
            #pragma unroll
            for (int j = 0; j < 4; ++j)
                acc[i][j] = __builtin_amdgcn_mfma_f32_16x16x32_bf16(af[i], bfr[j], acc[i][j], 0, 0, 0);
    }

    // fused epilogue: relu + dot with v over this wave's 64 cols, LDS-reduce 8 slices
    float u4[4], v4[4]; int h4[4];
    #pragma unroll
    for (int j = 0; j < 4; ++j) {
        int h = wn8*64 + j*16 + col;
        h4[j] = h; u4[j] = uw[h]; v4[j] = vv[h];
    }
    #pragma unroll
    for (int i = 0; i < 4; ++i) {
        #pragma unroll
        for (int r = 0; r < 4; ++r) {
            int b = wm2*64 + i*16 + quad*4 + r;
            float cv = cov[b*T_ + mt];
            float s = 0.f;
            #pragma unroll
            for (int j = 0; j < 4; ++j) {
                float val = acc[i][j][r] + A1w[b*H_ + h4[j]] + cv * u4[j];
                val = val > 0.f ? val : 0.f;
                s += val * v4[j];
            }
            #pragma unroll
            for (int off = 1; off < 16; off <<= 1) s += __shfl_xor(s, off, 64);
            if (col == 0) red[b][wn8] = s;
        }
    }
    __syncthreads();
    if (tid < 128) {
        float s = 0.f;
        #pragma unroll
        for (int w = 0; w < 8; ++w) s += red[tid][w];
        sc[(size_t)tid * T_ + mt] = s;    // [b][t] layout
    }
}

// ---------------- softmax over T + coverage outputs ----------------
__global__ void attn_softmax(const float* scores, const float* code_cov, const float* ast_cov,
                             float* wsm, float* out) {
    int b = blockIdx.x, which = blockIdx.y;
    const float* sc = scores + (size_t)which * M_ + (size_t)b * T_;
    const float* cov = which ? ast_cov : code_cov;
    float* wrow = wsm + ((size_t)which * B_ + b) * T_;
    float* w_out   = out + 3840000 + 65536 + (size_t)which * 65536 + b * T_;
    float* cov_out = out + 3840000 + 65536 + 131072 + (size_t)which * 65536 + b * T_;
    int tid = threadIdx.x;
    __shared__ float red[8];
    float v0 = sc[tid];
    float v1 = sc[tid + 256];
    float m = fmaxf(v0, v1);
    #pragma unroll
    for (int off = 32; off; off >>= 1) m = fmaxf(m, __shfl_xor(m, off, 64));
    if ((tid & 63) == 0) red[tid >> 6] = m;
    __syncthreads();
    m = fmaxf(fmaxf(red[0], red[1]), fmaxf(red[2], red[3]));
    float e0 = expf(v0 - m), e1 = expf(v1 - m);
    float s = e0 + e1;
    #pragma unroll
    for (int off = 32; off; off >>= 1) s += __shfl_xor(s, off, 64);
    if ((tid & 63) == 0) red[4 + (tid >> 6)] = s;
    __syncthreads();
    float inv = 1.f / (red[4] + red[5] + red[6] + red[7]);
    float w0 = e0 * inv, w1 = e1 * inv;
    wrow[tid] = w0; wrow[tid + 256] = w1;
    w_out[tid] = w0; w_out[tid + 256] = w1;
    cov_out[tid]       = cov[b*T_ + tid]       + w0;
    cov_out[tid + 256] = cov[b*T_ + tid + 256] + w1;
}

// ---------------- context: ctx[b,h] = 0.5*sum_t (wc*code + wa*ast) ----------------
__global__ void ctx_kernel(const float* code_enc, const float* ast_enc,
                           const float* wsm, float* x) {
    int b = blockIdx.x, tc = blockIdx.y;     // tc 0..7
    int tid = threadIdx.x;                   // 0..127
    __shared__ float wc[64], wa[64];
    if (tid < 64) {
        wc[tid] = wsm[(size_t)b * T_ + tc*64 + tid];
        wa[tid] = wsm[(size_t)(B_ + b) * T_ + tc*64 + tid];
    }
    __syncthreads();
    float a0=0.f, a1=0.f, a2=0.f, a3=0.f;
    for (int i = 0; i < 64; ++i) {
        int t = tc * 64 + i;
        float4 c4 = *(const float4*)(code_enc + (size_t)t * (B_*H_) + b*H_ + tid*4);
        float4 a4 = *(const float4*)(ast_enc  + (size_t)t * (B_*H_) + b*H_ + tid*4);
        a0 += wc[i]*c4.x + wa[i]*a4.x;
        a1 += wc[i]*c4.y + wa[i]*a4.y;
        a2 += wc[i]*c4.z + wa[i]*a4.z;
        a3 += wc[i]*c4.w + wa[i]*a4.w;
    }
    atomicAdd(&x[b*1024 + 512 + tid*4],     0.5f*a0);
    atomicAdd(&x[b*1024 + 512 + tid*4 + 1], 0.5f*a1);
    atomicAdd(&x[b*1024 + 512 + tid*4 + 2], 0.5f*a2);
    atomicAdd(&x[b*1024 + 512 + tid*4 + 3], 0.5f*a3);
}

// ---------------- GRU gate GEMMs ----------------
__global__ void gru_gemm(const float* x, const float* h0, const float* Wih, const float* Whh,
                         const float* bih, const float* bhh, float* g) {
    int nc = blockIdx.x;          // 0..23
    int bcb = blockIdx.y;         // 0..15
    int b0 = bcb * 8;
    int tid = threadIdx.x;
    __shared__ float xs[8][1024];   // 32 KB
    __shared__ float hs[8][512];    // 16 KB
    for (int idx = tid; idx < 2048; idx += 256) {
        int row = idx >> 8, c = (idx & 255) * 4;
        *(float4*)&xs[row][c] = *(const float4*)(x + (size_t)(b0+row)*1024 + c);
    }
    for (int idx = tid; idx < 1024; idx += 256) {
        int row = idx >> 7, c = (idx & 127) * 4;
        *(float4*)&hs[row][c] = *(const float4*)(h0 + (size_t)(b0+row)*512 + c);
    }
    __syncthreads();
    int n = nc * 64 + (tid & 63);
    int r0 = (tid >> 6) * 2, r1 = r0 + 1;
    const float* wi = Wih + (size_t)n * 1024;
    const float* wh = Whh + (size_t)n * 512;
    float si0=0.f, si1=0.f, sh0=0.f, sh1=0.f;
    for (int k = 0; k < 1024; k += 4) {
        float4 w  = *(const float4*)(wi + k);
        float4 x0 = *(const float4*)&xs[r0][k];
        float4 x1 = *(const float4*)&xs[r1][k];
        si0 += w.x*x0.x + w.y*x0.y + w.z*x0.z + w.w*x0.w;
        si1 += w.x*x1.x + w.y*x1.y + w.z*x1.z + w.w*x1.w;
    }
    for (int k = 0; k < 512; k += 4) {
        float4 w  = *(const float4*)(wh + k);
        float4 x0 = *(const float4*)&hs[r0][k];
        float4 x1 = *(const float4*)&hs[r1][k];
        sh0 += w.x*x0.x + w.y*x0.y + w.z*x0.z + w.w*x0.w;
        sh1 += w.x*x1.x + w.y*x1.y + w.z*x1.z + w.w*x1.w;
    }
    int gate = n >> 9, h = n & 511;
    float bi = bih[n], bh = bhh[n];
    int b;
    b = b0 + r0;
    {
        float A = si0 + bi, Bv = sh0 + bh;
        if (gate == 0)      g[b*512 + h] = A + Bv;
        else if (gate == 1) g[65536 + b*512 + h] = A + Bv;
        else { g[131072 + b*512 + h] = A; g[196608 + b*512 + h] = Bv; }
    }
    b = b0 + r1;
    {
        float A = si1 + bi, Bv = sh1 + bh;
        if (gate == 0)      g[b*512 + h] = A + Bv;
        else if (gate == 1) g[65536 + b*512 + h] = A + Bv;
        else { g[131072 + b*512 + h] = A; g[196608 + b*512 + h] = Bv; }
    }
}

__global__ void gru_finish(const float* g, const float* x, const float* h0,
                           float* out, float* y) {
    int i = blockIdx.x * 256 + threadIdx.x;   // 0..65535
    int b = i >> 9, h = i & 511;
    float r = 1.f / (1.f + expf(-g[i]));
    float z = 1.f / (1.f + expf(-g[65536 + i]));
    float nn = tanhf(g[131072 + i] + r * g[196608 + i]);
    float h1 = (1.f - z) * nn + z * h0[i];
    out[3840000 + i] = h1;
    y[b*1024 + h]       = h1;
    y[b*1024 + 512 + h] = x[b*1024 + 512 + h];
}

// ---------------- logits GEMM: [128,1024] @ W_out[30000,1024]^T + b_out ----------------
// Same dbuf single-barrier pipeline as attn_gemm. BK=32, 32 K-steps.
__global__ __launch_bounds__(256)
void logits_gemm(const float* y, const float* Wout, const float* bout, float* out0) {
    int n0 = blockIdx.x * 128;
    __shared__ __align__(16) ushort As[2][128 * ALS];   // 20 KB
    __shared__ __align__(16) ushort Bs[2][128 * ALS];   // 20 KB
    int tid = threadIdx.x, lane = tid & 63, wave = tid >> 6;
    int wm = wave >> 1, wn = wave & 1;
    int col = lane & 15, quad = lane >> 4;
    f32x4 acc[4][4];
    #pragma unroll
    for (int i = 0; i < 4; ++i)
        #pragma unroll
        for (int j = 0; j < 4; ++j) acc[i][j] = (f32x4)(0.f);

    // staging: idx = it*256 + tid (it 0..1): row = it*64 + (tid>>2), c8 = (tid&3)*8
    int srow = tid >> 2, sc8 = (tid & 3) * 8;
    int br0 = n0 + srow;       if (br0 > VOUT-1) br0 = VOUT-1;
    int br1 = n0 + 64 + srow;  if (br1 > VOUT-1) br1 = VOUT-1;
    const float* asrc0 = y + (size_t)srow * 1024 + sc8;
    const float* asrc1 = y + (size_t)(64 + srow) * 1024 + sc8;
    const float* bsrc0 = Wout + (size_t)br0 * 1024 + sc8;
    const float* bsrc1 = Wout + (size_t)br1 * 1024 + sc8;
    ushort* adst0 = &As[0][srow * ALS + sc8];
    ushort* adst1 = &As[0][(64 + srow) * ALS + sc8];
    ushort* bdst0 = &Bs[0][srow * ALS + sc8];
    ushort* bdst1 = &Bs[0][(64 + srow) * ALS + sc8];
    const int bufstep = 128 * ALS;

    float4 ya0a, ya0b, ya1a, ya1b, wb0a, wb0b, wb1a, wb1b;
    ya0a = *(const float4*)(asrc0); ya0b = *(const float4*)(asrc0 + 4);
    ya1a = *(const float4*)(asrc1); ya1b = *(const float4*)(asrc1 + 4);
    wb0a = *(const float4*)(bsrc0); wb0b = *(const float4*)(bsrc0 + 4);
    wb1a = *(const float4*)(bsrc1); wb1b = *(const float4*)(bsrc1 + 4);

    for (int kt = 0; kt < 32; ++kt) {
        int cur = kt & 1;
        *(short8*)(adst0 + cur * bufstep) = cvt8v(ya0a, ya0b);
        *(short8*)(adst1 + cur * bufstep) = cvt8v(ya1a, ya1b);
        *(short8*)(bdst0 + cur * bufstep) = cvt8v(wb0a, wb0b);
        *(short8*)(bdst1 + cur * bufstep) = cvt8v(wb1a, wb1b);
        __syncthreads();
        if (kt < 31) {
            int k0 = (kt + 1) * 32;
            ya0a = *(const float4*)(asrc0 + k0); ya0b = *(const float4*)(asrc0 + k0 + 4);
            ya1a = *(const float4*)(asrc1 + k0); ya1b = *(const float4*)(asrc1 + k0 + 4);
            wb0a = *(const float4*)(bsrc0 + k0); wb0b = *(const float4*)(bsrc0 + k0 + 4);
            wb1a = *(const float4*)(bsrc1 + k0); wb1b = *(const float4*)(bsrc1 + k0 + 4);
        }
        short8 af[4], bfr[4];
        #pragma unroll
        for (int i = 0; i < 4; ++i)
            af[i] = *(const short8*)(&As[cur][(wm*64 + i*16 + col) * ALS + quad*8]);
        #pragma unroll
        for (int j = 0; j < 4; ++j)
            bfr[j] = *(const short8*)(&Bs[cur][(wn*64 + j*16 + col) * ALS + quad*8]);
        #pragma unroll
        for (int i = 0; i < 4; ++i)
            #pragma unroll
            for (int j = 0; j < 4; ++j)
                acc[i][j] = __builtin_amdgcn_mfma_f32_16x16x32_bf16(af[i], bfr[j], acc[i][j], 0, 0, 0);
    }
    #pragma unroll
    for (int i = 0; i < 4; ++i)
        #pragma unroll
        for (int j = 0; j < 4; ++j) {
            int h = n0 + wn*64 + j*16 + col;
            if (h < VOUT) {
                float bo = bout[h];
                #pragma unroll
                for (int r = 0; r < 4; ++r) {
                    int m = wm*64 + i*16 + quad*4 + r;
                    out0[(size_t)m * VOUT + h] = acc[i][j][r] + bo;
                }
            }
        }
}

__global__ void logsoftmax(float* out0) {
    int b = blockIdx.x; int tid = threadIdx.x;
    float* row = out0 + (size_t)b * VOUT;
    __shared__ float red[8];
    float m = -1e30f;
    for (int i = tid; i < VOUT; i += 256) m = fmaxf(m, row[i]);
    #pragma unroll
    for (int off = 32; off; off >>= 1) m = fmaxf(m, __shfl_xor(m, off, 64));
    if ((tid & 63) == 0) red[tid >> 6] = m;
    __syncthreads();
    m = fmaxf(fmaxf(red[0], red[1]), fmaxf(red[2], red[3]));
    float s = 0.f;
    for (int i = tid; i < VOUT; i += 256) s += expf(row[i] - m);
    #pragma unroll
    for (int off = 32; off; off >>= 1) s += __shfl_xor(s, off, 64);
    if ((tid & 63) == 0) red[4 + (tid >> 6)] = s;
    __syncthreads();
    float lse = m + logf(red[4] + red[5] + red[6] + red[7]);
    for (int i = tid; i < VOUT; i += 256) row[i] = row[i] - lse;
}

// ---------------- launch ----------------
extern "C" void kernel_launch(void* const* d_in, const int* in_sizes, int n_in,
                              void* d_out, int out_size, void* d_ws, size_t ws_size,
                              hipStream_t stream) {
    const int*   inputs   = (const int*)d_in[0];
    const float* h0       = (const float*)d_in[1];
    const float* code_enc = (const float*)d_in[2];
    const float* ast_enc  = (const float*)d_in[3];
    const float* code_cov = (const float*)d_in[4];
    const float* ast_cov  = (const float*)d_in[5];
    const float* emb      = (const float*)d_in[6];
    const float* code_W   = (const float*)d_in[7];
    const float* code_b   = (const float*)d_in[8];
    const float* code_v   = (const float*)d_in[9];
    const float* code_Wc  = (const float*)d_in[10];
    const float* ast_W    = (const float*)d_in[11];
    const float* ast_b    = (const float*)d_in[12];
    const float* ast_v    = (const float*)d_in[13];
    const float* ast_Wc   = (const float*)d_in[14];
    const float* gru_Wih  = (const float*)d_in[15];
    const float* gru_Whh  = (const float*)d_in[16];
    const float* gru_bih  = (const float*)d_in[17];
    const float* gru_bhh  = (const float*)d_in[18];
    const float* W_out    = (const float*)d_in[19];
    const float* b_out    = (const float*)d_in[20];
    float* out = (float*)d_out;

    // workspace layout — 3.51 MB total
    char* ws = (char*)d_ws;
    float* scores = (float*)(ws + 0);          // 2*65536 f32   = 512 KB  ([which][b][t], fully written)
    float* x      = (float*)(ws + 524288);     // 128*1024 f32  = 512 KB  (zeroed; [.,512:) = ctx acc)
    float* A1     = (float*)(ws + 1048576);    // 2*128*512 f32 = 512 KB
    float* wsm    = (float*)(ws + 1572864);    // 2*128*512 f32 = 512 KB
    float* u      = (float*)(ws + 2097152);    // 2*512 f32     = 4 KB
    float* g      = (float*)(ws + 2101248);    // 4*128*512 f32 = 1 MB
    float* y      = (float*)(ws + 3149824);    // 128*1024 f32  = 512 KB

    hipMemsetAsync(ws + 524288, 0, 524288, stream);    // zero x (ctx accumulates)

    emb_gather<<<dim3(B_), dim3(256), 0, stream>>>(inputs, emb, x);
    prep_a1<<<dim3(8, 8, 2), dim3(256), 0, stream>>>(h0, code_W, code_b, ast_W, ast_b, A1);
    prep_u<<<dim3(2), dim3(512), 0, stream>>>(code_Wc, code_W, ast_Wc, ast_W, u);

    attn_gemm<<<dim3(512, 2), dim3(1024), 0, stream>>>(
        code_enc, ast_enc, code_W, ast_W, code_v, ast_v, code_cov, ast_cov, A1, u, scores);

    attn_softmax<<<dim3(B_, 2), dim3(256), 0, stream>>>(scores, code_cov, ast_cov, wsm, out);

    ctx_kernel<<<dim3(B_, 8), dim3(128), 0, stream>>>(code_enc, ast_enc, wsm, x);

    gru_gemm<<<dim3(24, 16), dim3(256), 0, stream>>>(x, h0, gru_Wih, gru_Whh, gru_bih, gru_bhh, g);
    gru_finish<<<dim3(256), dim3(256), 0, stream>>>(g, x, h0, out, y);

    logits_gemm<<<dim3(235), dim3(256), 0, stream>>>(y, W_out, b_out, out);
    logsoftmax<<<dim3(B_), dim3(256), 0, stream>>>(out);
}